// Round 5
// baseline (157.724 us; speedup 1.0000x reference)
//
#include <hip/hip_runtime.h>
#include <hip/hip_fp16.h>
#include <math.h>

// Caps1D dynamic routing — SINGLE-KERNEL: direct-fp32 W build (no repack
// prepass), TWO-STREAM named-register prefetch (10 loads in flight),
// fp16 u_ji in LDS, dot2 sweep, DPP/swizzle/permlane reductions.
//
// u: [B=1024, R=2336, M=4] fp32 ; W: [K=2, R=2336, M=4, P=16] fp32
// out[b,k] = norm/(1+norm) of final squashed routing sum.
//
// Measured history: r8 W-coalescing (162->112us steady), r10 depth-1
// named-reg prefetch + distributed squash (->85), r11 dot2 sweep (->77),
// r15 two-stream prefetch (->70; VGPR 52), r18 three-stream (127.6 total,
// routing ~70, 1.79M bank confl).
// r19 FAILED (143.9): DPP rewrite GOOD (confl 1.79M->0) but (512,4)
//   bounds => 64-VGPR cap + hoisted raw[] => 77MB scratch spills.
// r20 BEST (121.7 total, routing 62-65): DPP rewrite kept, regressions
//   reverted. VGPR 60, VALUBusy 58-61%, occ 37-38%.
// r21 FAILED (135.4, routing 80-84): 4-stream + raw[] hoist -> VGPR 76
//   -> 64-VGPR OCCUPANCY CLIFF (occ 37->21: 2 blocks/CU -> 1). HARD RULE:
//   <= 64 VGPRs. Deeper prefetch / cross-iter hoists are dead levers.
// r22 (120.8 total, routing 61.6-65.1): r20 restore, confirmed stable.
//   Constant ~58us gap between routing dispatch and total across ALL
//   rounds = w_repack dispatch + extra graph node + harness fixed cost.
// r23 (this): eliminate w_repack entirely — build reads W fp32 directly.
//   * Per (r,p2) row: 4x global float2 loads at ONE address + imm offsets
//     (+0/64/128/192B). 2 streams x (uu4 + 8 W floats) = 24 prefetch
//     VGPRs (same as r20's 24) but 10 loads in flight (vs 6): better MLP.
//   * u_ji = fp32 math, rounded to fp16 once (was: fp16 inputs) —
//     absmax should hold or improve.
//   * VALU +2 inst/row (8 fma vs 2 cvt + 4 fdot2) ~ +3%, offset by MLP.
//   * Tripwire: occ must stay ~37%; occ ~21% => VGPR crossed 64 => revert.
// FAILED branches (all measured): 1024-thr blocks (r2-4, r9), 768-thr
// blocks (r17), register-resident u_ji (r16), sched_barrier fences (r14),
// array-chunk pipelines (r11/r12), raw[] hoist + tight bounds (r19),
// VGPR>64 states (r21). MFMA sweep rejected on paper (exp replication).
// RULES (r12): arrays fully-unrolled constant-indexed, unconditionally
// initialized, no whole-array punning. 512 thr + launch_bounds(512,2).

#define THREADS 512
#define NWAVE 8
#define RR 2336
#define KK 2

#if __has_builtin(__builtin_amdgcn_fdot2)
typedef _Float16 h2v __attribute__((ext_vector_type(2)));
static __device__ __forceinline__ float dot2h(__half2 a, __half2 b, float c) {
    h2v av, bv;
    __builtin_memcpy(&av, &a, 4);
    __builtin_memcpy(&bv, &b, 4);
    return __builtin_amdgcn_fdot2(av, bv, c, false);
}
#else
static __device__ __forceinline__ float dot2h(__half2 a, __half2 b, float c) {
    float2 fa = __half22float2(a), fb = __half22float2(b);
    return fmaf(fa.x, fb.x, fmaf(fa.y, fb.y, c));
}
#endif

// ---- cross-lane add helpers (VALU-pipe DPP where possible) ----
#define DPP_XOR1 0xB1   // quad_perm [1,0,3,2]
#define DPP_XOR2 0x4E   // quad_perm [2,3,0,1]
#define DPP_ROR4 0x124  // row_ror:4
#define DPP_ROR8 0x128  // row_ror:8

template <int CTRL>
static __device__ __forceinline__ float dpp_addf(float x) {
    const int y = __builtin_amdgcn_update_dpp(0, __float_as_int(x), CTRL, 0xf, 0xf, true);
    return x + __int_as_float(y);
}
static __device__ __forceinline__ float swz16_addf(float x) {   // xor 16
    const int y = __builtin_amdgcn_ds_swizzle(__float_as_int(x), 0x401f);
    return x + __int_as_float(y);
}
#if __has_builtin(__builtin_amdgcn_permlane32_swap)
static __device__ __forceinline__ float pl32_addf(float x) {    // xor 32
    typedef unsigned uv2 __attribute__((ext_vector_type(2)));
    const uv2 r = __builtin_amdgcn_permlane32_swap(__float_as_uint(x), __float_as_uint(x),
                                                   false, false);
    return __uint_as_float(r[0]) + __uint_as_float(r[1]);
}
#else
static __device__ __forceinline__ float pl32_addf(float x) { return x + __shfl_xor(x, 32); }
#endif

// one stream's build step, direct-fp32 W (named scalars only)
#define STREAM_F32(base, i, uu, w0, w1, w2, w3)                               \
    {                                                                         \
        const int r = (base) + (i) * 64 + rbase;                              \
        const float ax = fmaf(uu.x, w0.x, fmaf(uu.y, w1.x,                    \
                         fmaf(uu.z, w2.x, uu.w * w3.x)));                     \
        const float ay = fmaf(uu.x, w0.y, fmaf(uu.y, w1.y,                    \
                         fmaf(uu.z, w2.y, uu.w * w3.y)));                     \
        sA += ax; sB += ay;                                                   \
        *(__half2*)(uji + r * 16 + p2 * 2) = __floats2half2_rn(ax, ay);       \
    }

// one routing-sweep step over a 16B half-row held in rw
#define SWEEP_STEP(rw)                                                     \
    {                                                                      \
        const __half2* hp = (const __half2*)&(rw);                         \
        float d = dot2h(hp[0], v2[0], dot2h(hp[1], v2[1],                  \
                  dot2h(hp[2], v2[2], dot2h(hp[3], v2[3], 0.0f))));        \
        d = dpp_addf<DPP_XOR1>(d);           /* join the two half-dots */  \
        const float e = __expf(d);           /* no max-subtract (bounded)*/\
        se += e;                                                           \
        { const float2 f0 = __half22float2(hp[0]);                         \
          s8[0] = fmaf(f0.x, e, s8[0]); s8[1] = fmaf(f0.y, e, s8[1]); }    \
        { const float2 f1 = __half22float2(hp[1]);                         \
          s8[2] = fmaf(f1.x, e, s8[2]); s8[3] = fmaf(f1.y, e, s8[3]); }    \
        { const float2 f2 = __half22float2(hp[2]);                         \
          s8[4] = fmaf(f2.x, e, s8[4]); s8[5] = fmaf(f2.y, e, s8[5]); }    \
        { const float2 f3 = __half22float2(hp[3]);                         \
          s8[6] = fmaf(f3.x, e, s8[6]); s8[7] = fmaf(f3.y, e, s8[7]); }    \
    }

__global__ __launch_bounds__(THREADS, 2)
void caps_routing_kernel(const float* __restrict__ u,
                         const float* __restrict__ W,
                         float* __restrict__ out)
{
    __shared__ __align__(16) __half uji[RR * 16];      // 74752 B
    __shared__ __align__(16) float  red[2][NWAVE][20]; // padded rows, f4-aligned
    __shared__ __align__(16) float  vrow[2][16];       // v vector hand-off

    const int bi   = blockIdx.x;                 // 2048 blocks
    const int b    = bi >> 1;
    const int k    = bi & 1;
    const int tid  = threadIdx.x;
    const int lane = tid & 63;
    const int wave = tid >> 6;
    const int p2   = lane & 7;                   // half2 column pair 0..7
    const int g    = lane >> 3;                  // row-in-group 0..7

    const float4* __restrict__ u4p = (const float4*)u;
    // per-thread W base: row r lives at Wf + r*64 floats; the 4 m-slices
    // are at +0/+16/+32/+48 floats (imm offsets of ONE address).
    const float* __restrict__ Wf = W + (size_t)k * RR * 64 + 2 * p2;

    // ---- build u_ji (fp32 math -> fp16 LDS) + iter-0 sums ----
    // TWO-stream prefetch: A rows [0,1152), B rows [1152,2304), 18 steps
    // each, guard-free; 10 loads in flight (2 u + 8 W).
    // Tail rows 2304..2335 = waves 0..3 (wave-uniform).
    float sA = 0.0f, sB = 0.0f;
    {
        const int rbase = wave * 8 + g;
        float4 uuA_n = u4p[b * RR + rbase];
        float2 wA0_n, wA1_n, wA2_n, wA3_n;
        {
            const float* wp = Wf + (size_t)rbase * 64;
            wA0_n = *(const float2*)(wp);
            wA1_n = *(const float2*)(wp + 16);
            wA2_n = *(const float2*)(wp + 32);
            wA3_n = *(const float2*)(wp + 48);
        }
        float4 uuB_n = u4p[b * RR + 1152 + rbase];
        float2 wB0_n, wB1_n, wB2_n, wB3_n;
        {
            const float* wp = Wf + (size_t)(1152 + rbase) * 64;
            wB0_n = *(const float2*)(wp);
            wB1_n = *(const float2*)(wp + 16);
            wB2_n = *(const float2*)(wp + 32);
            wB3_n = *(const float2*)(wp + 48);
        }
        #pragma unroll 3
        for (int i = 0; i < 18; ++i) {
            const float4 uuA = uuA_n;
            const float2 wA0 = wA0_n, wA1 = wA1_n, wA2 = wA2_n, wA3 = wA3_n;
            const float4 uuB = uuB_n;
            const float2 wB0 = wB0_n, wB1 = wB1_n, wB2 = wB2_n, wB3 = wB3_n;
            if (i + 1 < 18) {                    // prefetch both streams
                const int ra = (i + 1) * 64 + rbase;
                uuA_n = u4p[b * RR + ra];
                {
                    const float* wp = Wf + (size_t)ra * 64;
                    wA0_n = *(const float2*)(wp);
                    wA1_n = *(const float2*)(wp + 16);
                    wA2_n = *(const float2*)(wp + 32);
                    wA3_n = *(const float2*)(wp + 48);
                }
                const int rb = 1152 + ra;
                uuB_n = u4p[b * RR + rb];
                {
                    const float* wp = Wf + (size_t)rb * 64;
                    wB0_n = *(const float2*)(wp);
                    wB1_n = *(const float2*)(wp + 16);
                    wB2_n = *(const float2*)(wp + 32);
                    wB3_n = *(const float2*)(wp + 48);
                }
            }
            STREAM_F32(0,    i, uuA, wA0, wA1, wA2, wA3)
            STREAM_F32(1152, i, uuB, wB0, wB1, wB2, wB3)
        }
        if (wave < 4) {                          // tail rows 2304..2335
            const int r = 2304 + rbase;
            const float4 uu = u4p[b * RR + r];
            const float* wp = Wf + (size_t)r * 64;
            const float2 w0 = *(const float2*)(wp);
            const float2 w1 = *(const float2*)(wp + 16);
            const float2 w2 = *(const float2*)(wp + 32);
            const float2 w3 = *(const float2*)(wp + 48);
            const float ax = fmaf(uu.x, w0.x, fmaf(uu.y, w1.x,
                             fmaf(uu.z, w2.x, uu.w * w3.x)));
            const float ay = fmaf(uu.x, w0.y, fmaf(uu.y, w1.y,
                             fmaf(uu.z, w2.y, uu.w * w3.y)));
            sA += ax; sB += ay;
            *(__half2*)(uji + r * 16 + p2 * 2) = __floats2half2_rn(ax, ay);
        }
    }
    // iter-0 partials: reduce over g (xor8 -> DPP ror8, xor16 -> swizzle,
    // xor32 -> permlane32_swap; all preserve p2 = lane&7)
    sA = dpp_addf<DPP_ROR8>(sA);  sB = dpp_addf<DPP_ROR8>(sB);
    sA = swz16_addf(sA);          sB = swz16_addf(sB);
    sA = pl32_addf(sA);           sB = pl32_addf(sB);
    if (lane < 8) {
        red[0][wave][2 * p2]     = sA;
        red[0][wave][2 * p2 + 1] = sB;
    }
    __syncthreads();                             // barrier 1: uji + red[0] ready

    // ---- distributed squash, iter 0 (se == RR exactly); all-lane form ----
    float vcum_s;                                // this lane's cumulative v[lane&15]
    {
        float col = 0.0f;
        #pragma unroll
        for (int w = 0; w < NWAVE; ++w) col += red[0][w][lane & 15];
        float nr = col * col;
        nr = dpp_addf<DPP_XOR1>(nr);
        nr = dpp_addf<DPP_XOR2>(nr);
        nr = dpp_addf<DPP_ROR4>(nr);
        nr = dpp_addf<DPP_ROR8>(nr);             // row-replicated full 16-sum
        const float inv  = 1.0f / (float)RR;
        const float norm = nr * inv * inv;
        const float f    = sqrtf(norm) / (1.0f + norm);
        vcum_s = col * inv * f;
        if (lane < 16) vrow[0][lane] = vcum_s;   // benign same-value multi-wave write
    }

    // ---- iterations 1,2: sweep + distributed squash ----
    #pragma unroll 1
    for (int it = 1; it < 3; ++it) {
        const int buf = it & 1;

        __half2 v2[4];
        {
            const float2* vp = (const float2*)vrow[buf ^ 1];
            #pragma unroll
            for (int q = 0; q < 4; ++q) {
                const float2 pv = vp[(lane & 1) * 4 + q];
                v2[q] = __floats2half2_rn(pv.x, pv.y);
            }
        }

        // u_ji row slice: steps 0..8 guard-free (max row 2303); step 9 is
        // rows 2304..2335, wave-uniform (only wave 0 consumes it).
        // Loaded per-iteration on purpose: hoisting costs ~16 live VGPRs
        // across the it-loop and tips the 64-VGPR occupancy cliff (r21).
        float4 raw[9], raw9;
        {
            const int rb = wave * 32 + (lane >> 1);
            #pragma unroll
            for (int s = 0; s < 9; ++s)
                raw[s] = *(const float4*)((const char*)uji + (s * 256 + rb) * 32 + (lane & 1) * 16);
            raw9 = *(const float4*)((const char*)uji + (2304 + (lane >> 1)) * 32 + (lane & 1) * 16);
        }

        float s8[8] = {0, 0, 0, 0, 0, 0, 0, 0};
        float se = 0.0f;
        #pragma unroll
        for (int s = 0; s < 9; ++s) SWEEP_STEP(raw[s])
        if (wave == 0) SWEEP_STEP(raw9)          // wave-uniform tail step

        // parity-preserving reduction: 3 DPP + 1 swizzle + 1 permlane per var
        #pragma unroll
        for (int i = 0; i < 8; ++i) {
            s8[i] = dpp_addf<DPP_XOR2>(s8[i]);
            s8[i] = dpp_addf<DPP_ROR4>(s8[i]);
            s8[i] = dpp_addf<DPP_ROR8>(s8[i]);
            s8[i] = swz16_addf(s8[i]);
            s8[i] = pl32_addf(s8[i]);
        }
        se = dpp_addf<DPP_XOR2>(se);
        se = dpp_addf<DPP_ROR4>(se);
        se = dpp_addf<DPP_ROR8>(se);
        se = swz16_addf(se);
        se = pl32_addf(se);

        if (lane < 2) {
            *(float4*)&red[buf][wave][(lane & 1) * 8]     = make_float4(s8[0], s8[1], s8[2], s8[3]);
            *(float4*)&red[buf][wave][(lane & 1) * 8 + 4] = make_float4(s8[4], s8[5], s8[6], s8[7]);
            if (lane == 0) red[buf][wave][16] = se;
        }
        __syncthreads();                         // barrier 2 / 3

        // distributed squash from red[buf] (all-lane form)
        {
            float col = 0.0f, set = 0.0f;
            #pragma unroll
            for (int w = 0; w < NWAVE; ++w) {
                col += red[buf][w][lane & 15];
                set += red[buf][w][16];          // broadcast reads
            }
            float nr = col * col;
            nr = dpp_addf<DPP_XOR1>(nr);
            nr = dpp_addf<DPP_XOR2>(nr);
            nr = dpp_addf<DPP_ROR4>(nr);
            nr = dpp_addf<DPP_ROR8>(nr);
            const float inv  = 1.0f / set;
            const float norm = nr * inv * inv;
            if (it == 1) {
                const float f = sqrtf(norm) / (1.0f + norm);
                vcum_s += col * inv * f;
                if (lane < 16) vrow[1][lane] = vcum_s;
            } else if (wave == 0 && lane == 0) {
                out[b * KK + k] = norm / (1.0f + norm);
            }
        }
    }
}

extern "C" void kernel_launch(void* const* d_in, const int* in_sizes, int n_in,
                              void* d_out, int out_size, void* d_ws, size_t ws_size,
                              hipStream_t stream) {
    const float* u = (const float*)d_in[0];   // [1024, 2336, 4]
    const float* W = (const float*)d_in[1];   // [2, 2336, 4, 16]
    float* out = (float*)d_out;               // [1024, 2]
    (void)d_ws; (void)ws_size;                // no repack scratch needed anymore

    caps_routing_kernel<<<dim3(2048), dim3(THREADS), 0, stream>>>(u, W, out);
}